// Round 1
// baseline (459.661 us; speedup 1.0000x reference)
//
#include <hip/hip_runtime.h>
#include <math.h>

#define NUM_GROUPS 100
#define GROUP_SIZE 100
#define TOTAL_ROWS 10000
#define NUM_CLASSES 1000
#define BATCH 4096
#define EPS 1e-12f

// ---------------------------------------------------------------------------
// Kernel 1: per-(group, class) softmax over the GROUP_SIZE rows, then log(+eps)
// Layout: W[r, c], r = g*GROUP_SIZE + rr, contiguous in c (stride 1 in class).
// grid = (NUM_GROUPS, 4), block = 256; each thread owns one class column
// (250 classes per blockIdx.y chunk). 3 passes over the 100 strided values:
// max, sum-exp, write. Pass 1 comes from HBM, passes 2-3 hit L2 (400 KB/group).
// ---------------------------------------------------------------------------
__global__ __launch_bounds__(256)
void group_log_softmax_kernel(const float* __restrict__ W,
                              float* __restrict__ logW) {
    const int g   = blockIdx.x;
    const int c   = blockIdx.y * 250 + threadIdx.x;
    if (threadIdx.x >= 250) return;

    const float* Wg = W    + (size_t)g * GROUP_SIZE * NUM_CLASSES + c;
    float*       Lg = logW + (size_t)g * GROUP_SIZE * NUM_CLASSES + c;

    float m = -INFINITY;
    #pragma unroll 4
    for (int r = 0; r < GROUP_SIZE; ++r)
        m = fmaxf(m, Wg[r * NUM_CLASSES]);

    float s = 0.0f;
    #pragma unroll 4
    for (int r = 0; r < GROUP_SIZE; ++r)
        s += expf(Wg[r * NUM_CLASSES] - m);

    const float inv = 1.0f / s;
    #pragma unroll 4
    for (int r = 0; r < GROUP_SIZE; ++r) {
        float t = expf(Wg[r * NUM_CLASSES] - m) * inv;
        Lg[r * NUM_CLASSES] = logf(t + EPS);
    }
}

// ---------------------------------------------------------------------------
// Kernel 2: one block per sample.
//  Phase 0: scan x_onehot[b, :] (float4), record the single active row per
//           group into LDS (exactly one 1.0 per group -> no write race).
//  Phase 1: 250 active threads, 4 consecutive classes each (float4);
//           acc = bias + sum_g logW[row_g, c]; coalesced 4 KB row reads.
//  Phase 2: block softmax over 1000 classes (wave shfl + LDS), float4 store.
// ---------------------------------------------------------------------------
__global__ __launch_bounds__(256)
void gather_softmax_kernel(const float* __restrict__ x,
                           const float* __restrict__ logW,
                           const float* __restrict__ bias,
                           float* __restrict__ out) {
    __shared__ int   idx_s[NUM_GROUPS];
    __shared__ float red_s[5];

    const int b   = blockIdx.x;
    const int tid = threadIdx.x;

    // Phase 0: find one-hot indices (10000 floats = 2500 float4)
    const float4* xrow = (const float4*)(x + (size_t)b * TOTAL_ROWS);
    for (int j4 = tid; j4 < TOTAL_ROWS / 4; j4 += 256) {
        float4 v = xrow[j4];
        int j = j4 * 4;
        if (v.x > 0.5f) idx_s[(j + 0) / GROUP_SIZE] = j + 0;
        if (v.y > 0.5f) idx_s[(j + 1) / GROUP_SIZE] = j + 1;
        if (v.z > 0.5f) idx_s[(j + 2) / GROUP_SIZE] = j + 2;
        if (v.w > 0.5f) idx_s[(j + 3) / GROUP_SIZE] = j + 3;
    }
    __syncthreads();

    // Phase 1: gather-accumulate
    const bool active = (tid < NUM_CLASSES / 4);   // 250 threads
    const int  c      = tid * 4;
    float4 acc = make_float4(0.f, 0.f, 0.f, 0.f);
    if (active) {
        acc = *(const float4*)(bias + c);
        #pragma unroll 4
        for (int g = 0; g < NUM_GROUPS; ++g) {
            const int row = idx_s[g];
            float4 w = *(const float4*)(logW + (size_t)row * NUM_CLASSES + c);
            acc.x += w.x; acc.y += w.y; acc.z += w.z; acc.w += w.w;
        }
    }

    // Phase 2a: block max
    float m = active ? fmaxf(fmaxf(acc.x, acc.y), fmaxf(acc.z, acc.w))
                     : -INFINITY;
    #pragma unroll
    for (int off = 32; off > 0; off >>= 1)
        m = fmaxf(m, __shfl_down(m, off, 64));
    if ((tid & 63) == 0) red_s[tid >> 6] = m;
    __syncthreads();
    if (tid == 0) {
        float mm = fmaxf(fmaxf(red_s[0], red_s[1]), fmaxf(red_s[2], red_s[3]));
        red_s[4] = mm;
    }
    __syncthreads();
    const float M = red_s[4];

    // Phase 2b: exp + block sum
    float4 e = make_float4(0.f, 0.f, 0.f, 0.f);
    float ls = 0.0f;
    if (active) {
        e.x = expf(acc.x - M); e.y = expf(acc.y - M);
        e.z = expf(acc.z - M); e.w = expf(acc.w - M);
        ls = (e.x + e.y) + (e.z + e.w);
    }
    #pragma unroll
    for (int off = 32; off > 0; off >>= 1)
        ls += __shfl_down(ls, off, 64);
    if ((tid & 63) == 0) red_s[tid >> 6] = ls;
    __syncthreads();
    if (tid == 0)
        red_s[4] = (red_s[0] + red_s[1]) + (red_s[2] + red_s[3]);
    __syncthreads();
    const float inv = 1.0f / red_s[4];

    if (active) {
        float4 o = make_float4(e.x * inv, e.y * inv, e.z * inv, e.w * inv);
        *((float4*)(out + (size_t)b * NUM_CLASSES + c)) = o;
    }
}

extern "C" void kernel_launch(void* const* d_in, const int* in_sizes, int n_in,
                              void* d_out, int out_size, void* d_ws, size_t ws_size,
                              hipStream_t stream) {
    const float* x    = (const float*)d_in[0];  // (4096, 10000)
    const float* W    = (const float*)d_in[1];  // (10000, 1000)
    const float* bias = (const float*)d_in[2];  // (1000,)
    float* out  = (float*)d_out;                // (4096, 1000)
    float* logW = (float*)d_ws;                 // 10000*1000*4 = 40 MB scratch

    dim3 g1(NUM_GROUPS, 4);
    group_log_softmax_kernel<<<g1, 256, 0, stream>>>(W, logW);

    gather_softmax_kernel<<<BATCH, 256, 0, stream>>>(x, logW, bias, out);
}

// Round 2
// 399.909 us; speedup vs baseline: 1.1494x; 1.1494x over previous
//
#include <hip/hip_runtime.h>
#include <math.h>

#define NUM_GROUPS 100
#define GROUP_SIZE 100
#define TOTAL_ROWS 10000
#define NUM_CLASSES 1000
#define BATCH 4096
#define SPB 4                      // samples per gather block
#define GATHER_BLOCKS (BATCH / SPB)

// ---------------------------------------------------------------------------
// base[c] = bias[c]; corr accumulated into it by corr_kernel via atomicAdd.
// ---------------------------------------------------------------------------
__global__ __launch_bounds__(256)
void init_base_kernel(const float* __restrict__ bias, float* __restrict__ base) {
    int c = blockIdx.x * 256 + threadIdx.x;
    if (c < NUM_CLASSES) base[c] = bias[c];
}

// ---------------------------------------------------------------------------
// corr_kernel: base[c] -= (m[g,c] + log(sum_r exp(W[g,r,c]-m))) for group g.
// grid = (100 groups, 8 class-chunks of 125), block 256 = 125 classes x 2
// row-halves (50 rows each). Native __expf/__logf (v_exp/v_log). Two passes;
// pass 2 hits L2 (50 KB slab/block). atomicAdd: 100 adds per class, spread.
// ---------------------------------------------------------------------------
__global__ __launch_bounds__(256)
void corr_kernel(const float* __restrict__ W, float* __restrict__ base) {
    __shared__ float sh[2][125];
    const int g   = blockIdx.x;
    const int tid = threadIdx.x;
    const int cl  = tid % 125;
    const int q   = tid / 125;          // 0,1 active; q==2 (tid>=250) idle
    const int c   = blockIdx.y * 125 + cl;
    const bool act = (q < 2);

    const float* Wp = W + (size_t)(g * GROUP_SIZE + q * 50) * NUM_CLASSES + c;

    float m = -INFINITY;
    if (act) {
        #pragma unroll 10
        for (int r = 0; r < 50; ++r)
            m = fmaxf(m, Wp[r * NUM_CLASSES]);
        sh[q][cl] = m;
    }
    __syncthreads();
    const float M = act ? fmaxf(sh[0][cl], sh[1][cl]) : 0.0f;
    __syncthreads();                    // sh reused below

    if (act) {
        float s = 0.0f;
        #pragma unroll 10
        for (int r = 0; r < 50; ++r)
            s += __expf(Wp[r * NUM_CLASSES] - M);
        sh[q][cl] = s;
    }
    __syncthreads();
    if (q == 0) {
        float S = sh[0][cl] + sh[1][cl];
        atomicAdd(base + c, -(M + __logf(S)));
    }
}

// ---------------------------------------------------------------------------
// extract_kernel: streaming scan of x_onehot (float4), writes transposed
// index table idxT[g*BATCH + b] = global row id. 164 MB read, 1.6 MB write.
// A float4 never crosses a group boundary (100 % 4 == 0) -> g = r4/25.
// ---------------------------------------------------------------------------
__global__ __launch_bounds__(256)
void extract_kernel(const float* __restrict__ x, int* __restrict__ idxT) {
    const int total4 = BATCH * (TOTAL_ROWS / 4);     // 10,240,000
    for (int i = blockIdx.x * 256 + threadIdx.x; i < total4;
         i += gridDim.x * 256) {
        float4 v = ((const float4*)x)[i];
        if (v.x > 0.5f || v.y > 0.5f || v.z > 0.5f || v.w > 0.5f) {
            int b  = i / 2500;
            int r4 = i - b * 2500;
            int g  = r4 / 25;
            int j  = r4 * 4;
            int* dst = idxT + g * BATCH + b;
            if (v.x > 0.5f) *dst = j + 0;
            if (v.y > 0.5f) *dst = j + 1;
            if (v.z > 0.5f) *dst = j + 2;
            if (v.w > 0.5f) *dst = j + 3;
        }
    }
}

// ---------------------------------------------------------------------------
// gather_softmax_kernel: 1024 blocks x 4 samples. Per group g: one uniform
// int4 load of 4 row ids (readfirstlane -> SALU addressing), 4 independent
// float4 row reads from raw W (L2-hot: all blocks sweep groups in the same
// order, 400 KB slab per group per XCD). acc starts at 0 (small values),
// base[c] (~-465) added at the end to avoid big+small rounding in the loop.
// Epilogue: 4 block softmaxes, batched reductions (3 barriers total).
// ---------------------------------------------------------------------------
__global__ __launch_bounds__(256)
void gather_softmax_kernel(const int* __restrict__ idxT,
                           const float* __restrict__ W,
                           const float* __restrict__ base,
                           float* __restrict__ out) {
    __shared__ float red[SPB][4];
    __shared__ float fin[SPB];

    const int b0   = blockIdx.x * SPB;
    const int tid  = threadIdx.x;
    const bool act = (tid < NUM_CLASSES / 4);        // 250 active
    const int c    = (act ? tid : 249) * 4;          // clamp: no divergence
    const int lane = tid & 63;
    const int wv   = tid >> 6;

    float4 acc[SPB];
    #pragma unroll
    for (int s = 0; s < SPB; ++s) acc[s] = make_float4(0.f, 0.f, 0.f, 0.f);

    #pragma unroll 2
    for (int g = 0; g < NUM_GROUPS; ++g) {
        int4 rows = *(const int4*)(idxT + g * BATCH + b0);
        int r0 = __builtin_amdgcn_readfirstlane(rows.x);
        int r1 = __builtin_amdgcn_readfirstlane(rows.y);
        int r2 = __builtin_amdgcn_readfirstlane(rows.z);
        int r3 = __builtin_amdgcn_readfirstlane(rows.w);
        float4 w0 = *(const float4*)(W + r0 * NUM_CLASSES + c);
        float4 w1 = *(const float4*)(W + r1 * NUM_CLASSES + c);
        float4 w2 = *(const float4*)(W + r2 * NUM_CLASSES + c);
        float4 w3 = *(const float4*)(W + r3 * NUM_CLASSES + c);
        acc[0].x += w0.x; acc[0].y += w0.y; acc[0].z += w0.z; acc[0].w += w0.w;
        acc[1].x += w1.x; acc[1].y += w1.y; acc[1].z += w1.z; acc[1].w += w1.w;
        acc[2].x += w2.x; acc[2].y += w2.y; acc[2].z += w2.z; acc[2].w += w2.w;
        acc[3].x += w3.x; acc[3].y += w3.y; acc[3].z += w3.z; acc[3].w += w3.w;
    }

    const float4 bb = *(const float4*)(base + c);
    #pragma unroll
    for (int s = 0; s < SPB; ++s) {
        acc[s].x += bb.x; acc[s].y += bb.y; acc[s].z += bb.z; acc[s].w += bb.w;
    }

    // ---- block max per sample (shuffle within wave, LDS across waves) ----
    float m[SPB];
    #pragma unroll
    for (int s = 0; s < SPB; ++s) {
        m[s] = act ? fmaxf(fmaxf(acc[s].x, acc[s].y), fmaxf(acc[s].z, acc[s].w))
                   : -INFINITY;
        #pragma unroll
        for (int off = 32; off > 0; off >>= 1)
            m[s] = fmaxf(m[s], __shfl_down(m[s], off, 64));
    }
    if (lane == 0) {
        #pragma unroll
        for (int s = 0; s < SPB; ++s) red[s][wv] = m[s];
    }
    __syncthreads();
    float M[SPB];
    #pragma unroll
    for (int s = 0; s < SPB; ++s)
        M[s] = fmaxf(fmaxf(red[s][0], red[s][1]), fmaxf(red[s][2], red[s][3]));
    __syncthreads();                                  // before red reuse

    // ---- exp + block sum per sample ----
    float4 e[SPB];
    float ls[SPB];
    #pragma unroll
    for (int s = 0; s < SPB; ++s) {
        e[s].x = __expf(acc[s].x - M[s]);
        e[s].y = __expf(acc[s].y - M[s]);
        e[s].z = __expf(acc[s].z - M[s]);
        e[s].w = __expf(acc[s].w - M[s]);
        ls[s] = act ? (e[s].x + e[s].y) + (e[s].z + e[s].w) : 0.0f;
        #pragma unroll
        for (int off = 32; off > 0; off >>= 1)
            ls[s] += __shfl_down(ls[s], off, 64);
    }
    if (lane == 0) {
        #pragma unroll
        for (int s = 0; s < SPB; ++s) red[s][wv] = ls[s];
    }
    __syncthreads();
    #pragma unroll
    for (int s = 0; s < SPB; ++s)
        fin[s] = (red[s][0] + red[s][1]) + (red[s][2] + red[s][3]);

    if (act) {
        #pragma unroll
        for (int s = 0; s < SPB; ++s) {
            float inv = 1.0f / fin[s];
            float4 o = make_float4(e[s].x * inv, e[s].y * inv,
                                   e[s].z * inv, e[s].w * inv);
            *(float4*)(out + (size_t)(b0 + s) * NUM_CLASSES + c) = o;
        }
    }
}

extern "C" void kernel_launch(void* const* d_in, const int* in_sizes, int n_in,
                              void* d_out, int out_size, void* d_ws, size_t ws_size,
                              hipStream_t stream) {
    const float* x    = (const float*)d_in[0];  // (4096, 10000)
    const float* W    = (const float*)d_in[1];  // (10000, 1000)
    const float* bias = (const float*)d_in[2];  // (1000,)
    float* out  = (float*)d_out;                // (4096, 1000)

    float* base = (float*)d_ws;                               // 4 KB
    int*   idxT = (int*)((char*)d_ws + 4096);                 // 100*4096*4 = 1.6 MB

    init_base_kernel<<<4, 256, 0, stream>>>(bias, base);

    dim3 gc(NUM_GROUPS, 8);
    corr_kernel<<<gc, 256, 0, stream>>>(W, base);

    extract_kernel<<<2048, 256, 0, stream>>>(x, idxT);

    gather_softmax_kernel<<<GATHER_BLOCKS, 256, 0, stream>>>(idxT, W, base, out);
}

// Round 3
// 359.875 us; speedup vs baseline: 1.2773x; 1.1112x over previous
//
#include <hip/hip_runtime.h>
#include <math.h>

#define NUM_GROUPS 100
#define GROUP_SIZE 100
#define TOTAL_ROWS 10000
#define NUM_CLASSES 1000
#define BATCH 4096
#define SPB 2                      // samples per gather block
#define GATHER_BLOCKS (BATCH / SPB)

// bf16 helpers: pack with RTNE, unpack via shift (bf16->fp32 is exact)
__device__ __forceinline__ unsigned int f2bf(float f) {
    unsigned int u = __float_as_uint(f);
    return (u + 0x7FFFu + ((u >> 16) & 1u)) >> 16;
}
__device__ __forceinline__ float bflo(unsigned int p) { return __uint_as_float(p << 16); }
__device__ __forceinline__ float bfhi(unsigned int p) { return __uint_as_float(p & 0xFFFF0000u); }

// ---------------------------------------------------------------------------
__global__ __launch_bounds__(256)
void k_init_base(const float* __restrict__ bias, float* __restrict__ base) {
    int c = blockIdx.x * 256 + threadIdx.x;
    if (c < NUM_CLASSES) base[c] = bias[c];
}

// ---------------------------------------------------------------------------
// k_corr: base[c] -= (m[g,c] + log(sum_r exp(W[g,r,c]-m))). Unchanged from R2
// (now named for dispatch attribution). fp32 W, native transcendentals.
// ---------------------------------------------------------------------------
__global__ __launch_bounds__(256)
void k_corr(const float* __restrict__ W, float* __restrict__ base) {
    __shared__ float sh[2][125];
    const int g   = blockIdx.x;
    const int tid = threadIdx.x;
    const int cl  = tid % 125;
    const int q   = tid / 125;          // 0,1 active; tid>=250 idle
    const int c   = blockIdx.y * 125 + cl;
    const bool act = (q < 2);

    const float* Wp = W + (size_t)(g * GROUP_SIZE + q * 50) * NUM_CLASSES + c;

    float m = -INFINITY;
    if (act) {
        #pragma unroll 10
        for (int r = 0; r < 50; ++r)
            m = fmaxf(m, Wp[r * NUM_CLASSES]);
        sh[q][cl] = m;
    }
    __syncthreads();
    const float M = act ? fmaxf(sh[0][cl], sh[1][cl]) : 0.0f;
    __syncthreads();

    if (act) {
        float s = 0.0f;
        #pragma unroll 10
        for (int r = 0; r < 50; ++r)
            s += __expf(Wp[r * NUM_CLASSES] - M);
        sh[q][cl] = s;
    }
    __syncthreads();
    if (q == 0) {
        float S = sh[0][cl] + sh[1][cl];
        atomicAdd(base + c, -(M + __logf(S)));
    }
}

// ---------------------------------------------------------------------------
// k_cvt: W (fp32) -> Wh2 (bf16 packed, 2 per uint). 2500 blocks x 1000 float4.
// Halves the gather kernel's per-row bytes (4 KB -> 2 KB).
// ---------------------------------------------------------------------------
__global__ __launch_bounds__(256)
void k_cvt(const float* __restrict__ W, uint2* __restrict__ Wh2) {
    const float4* W4 = (const float4*)W;
    const int base4 = blockIdx.x * 1000;
    for (int j = threadIdx.x; j < 1000; j += 256) {
        float4 v = W4[base4 + j];
        unsigned int lo = f2bf(v.x) | (f2bf(v.y) << 16);
        unsigned int hi = f2bf(v.z) | (f2bf(v.w) << 16);
        Wh2[base4 + j] = make_uint2(lo, hi);
    }
}

// ---------------------------------------------------------------------------
// k_extract: scan x_onehot, write idxB[b*100+g] = global row id (b-major so
// the gather's LDS stage is one coalesced load). 2500 blocks x 4096 float4
// chunks (exact, no tail). Manual unroll x4 -> 4 independent loads in flight.
// ---------------------------------------------------------------------------
__global__ __launch_bounds__(256)
void k_extract(const float* __restrict__ x, int* __restrict__ idxB) {
    const float4* x4 = (const float4*)x;
    const int base = blockIdx.x * 4096 + threadIdx.x;
    #pragma unroll
    for (int k = 0; k < 16; k += 4) {
        float4 v[4];
        #pragma unroll
        for (int u = 0; u < 4; ++u)
            v[u] = x4[base + (k + u) * 256];
        #pragma unroll
        for (int u = 0; u < 4; ++u) {
            float4 vv = v[u];
            if (vv.x > 0.5f || vv.y > 0.5f || vv.z > 0.5f || vv.w > 0.5f) {
                int i  = base + (k + u) * 256;   // global float4 index
                int b  = i / 2500;
                int r4 = i - b * 2500;
                int g  = r4 / 25;                // 100 % 4 == 0: no boundary cross
                int j  = r4 * 4;
                int val = vv.x > 0.5f ? j
                        : (vv.y > 0.5f ? j + 1 : (vv.z > 0.5f ? j + 2 : j + 3));
                idxB[b * NUM_GROUPS + g] = val;
            }
        }
    }
}

// ---------------------------------------------------------------------------
// k_gather: 2048 blocks x 2 samples (8 blocks/CU = full occupancy).
// All 200 row ids staged to LDS up front (one coalesced 800 B load) -> the
// group loop has no global-index dependency; unroll x4 keeps 8 independent
// 512 B wave-loads of bf16 rows in flight. fp32 accumulate, base added at end,
// block softmax epilogue.
// ---------------------------------------------------------------------------
__global__ __launch_bounds__(256, 8)
void k_gather(const int* __restrict__ idxB, const uint2* __restrict__ Wh2,
              const float* __restrict__ base, float* __restrict__ out) {
    __shared__ int   idx_s[SPB * NUM_GROUPS];
    __shared__ float red[SPB][4];
    __shared__ float fin[SPB];

    const int b0  = blockIdx.x * SPB;
    const int tid = threadIdx.x;
    if (tid < SPB * NUM_GROUPS) idx_s[tid] = idxB[b0 * NUM_GROUPS + tid];
    __syncthreads();

    const bool act  = (tid < NUM_CLASSES / 4);      // 250 active
    const int  ct   = act ? tid : 249;              // class-quad, clamped
    const int  lane = tid & 63;
    const int  wv   = tid >> 6;

    float acc[SPB][4];
    #pragma unroll
    for (int s = 0; s < SPB; ++s)
        #pragma unroll
        for (int k = 0; k < 4; ++k) acc[s][k] = 0.0f;

    for (int g = 0; g < NUM_GROUPS; g += 4) {
        uint2 w[4][SPB];
        #pragma unroll
        for (int u = 0; u < 4; ++u)
            #pragma unroll
            for (int s = 0; s < SPB; ++s) {
                int r = __builtin_amdgcn_readfirstlane(idx_s[s * NUM_GROUPS + g + u]);
                w[u][s] = Wh2[r * (NUM_CLASSES / 4) + ct];   // 8 B = 4 bf16
            }
        #pragma unroll
        for (int u = 0; u < 4; ++u)
            #pragma unroll
            for (int s = 0; s < SPB; ++s) {
                acc[s][0] += bflo(w[u][s].x);
                acc[s][1] += bfhi(w[u][s].x);
                acc[s][2] += bflo(w[u][s].y);
                acc[s][3] += bfhi(w[u][s].y);
            }
    }

    const float4 bb = *(const float4*)(base + ct * 4);
    #pragma unroll
    for (int s = 0; s < SPB; ++s) {
        acc[s][0] += bb.x; acc[s][1] += bb.y;
        acc[s][2] += bb.z; acc[s][3] += bb.w;
    }

    // block max per sample
    float m[SPB];
    #pragma unroll
    for (int s = 0; s < SPB; ++s) {
        m[s] = act ? fmaxf(fmaxf(acc[s][0], acc[s][1]), fmaxf(acc[s][2], acc[s][3]))
                   : -INFINITY;
        #pragma unroll
        for (int off = 32; off > 0; off >>= 1)
            m[s] = fmaxf(m[s], __shfl_down(m[s], off, 64));
    }
    if (lane == 0) {
        #pragma unroll
        for (int s = 0; s < SPB; ++s) red[s][wv] = m[s];
    }
    __syncthreads();
    float M[SPB];
    #pragma unroll
    for (int s = 0; s < SPB; ++s)
        M[s] = fmaxf(fmaxf(red[s][0], red[s][1]), fmaxf(red[s][2], red[s][3]));
    __syncthreads();

    // exp + block sum per sample
    float e[SPB][4];
    float ls[SPB];
    #pragma unroll
    for (int s = 0; s < SPB; ++s) {
        e[s][0] = __expf(acc[s][0] - M[s]);
        e[s][1] = __expf(acc[s][1] - M[s]);
        e[s][2] = __expf(acc[s][2] - M[s]);
        e[s][3] = __expf(acc[s][3] - M[s]);
        ls[s] = act ? (e[s][0] + e[s][1]) + (e[s][2] + e[s][3]) : 0.0f;
        #pragma unroll
        for (int off = 32; off > 0; off >>= 1)
            ls[s] += __shfl_down(ls[s], off, 64);
    }
    if (lane == 0) {
        #pragma unroll
        for (int s = 0; s < SPB; ++s) red[s][wv] = ls[s];
    }
    __syncthreads();
    #pragma unroll
    for (int s = 0; s < SPB; ++s)
        fin[s] = (red[s][0] + red[s][1]) + (red[s][2] + red[s][3]);

    if (act) {
        #pragma unroll
        for (int s = 0; s < SPB; ++s) {
            float inv = 1.0f / fin[s];
            float4 o = make_float4(e[s][0] * inv, e[s][1] * inv,
                                   e[s][2] * inv, e[s][3] * inv);
            *(float4*)(out + (size_t)(b0 + s) * NUM_CLASSES + ct * 4) = o;
        }
    }
}

extern "C" void kernel_launch(void* const* d_in, const int* in_sizes, int n_in,
                              void* d_out, int out_size, void* d_ws, size_t ws_size,
                              hipStream_t stream) {
    const float* x    = (const float*)d_in[0];  // (4096, 10000)
    const float* W    = (const float*)d_in[1];  // (10000, 1000)
    const float* bias = (const float*)d_in[2];  // (1000,)
    float* out = (float*)d_out;                 // (4096, 1000)

    char* ws = (char*)d_ws;
    float* base = (float*)ws;                               // 4 KB
    int*   idxB = (int*)(ws + 4096);                        // 1.6 MB
    uint2* Wh2  = (uint2*)(ws + 4096 + BATCH * NUM_GROUPS * 4);  // 20 MB

    k_init_base<<<4, 256, 0, stream>>>(bias, base);
    k_cvt<<<2500, 256, 0, stream>>>(W, Wh2);
    dim3 gc(NUM_GROUPS, 8);
    k_corr<<<gc, 256, 0, stream>>>(W, base);
    k_extract<<<2500, 256, 0, stream>>>(x, idxB);
    k_gather<<<GATHER_BLOCKS, 256, 0, stream>>>(idxB, Wh2, base, out);
}